// Round 10
// baseline (313.830 us; speedup 1.0000x reference)
//
#include <hip/hip_runtime.h>
#include <math.h>

typedef unsigned short u16;
typedef float floatx4 __attribute__((ext_vector_type(4)));
typedef __bf16 bf16x8 __attribute__((ext_vector_type(8)));
typedef u16 u16x4 __attribute__((ext_vector_type(4)));

#define BB 2
#define SS 2048
#define HH 1024
#define NHEAD 16

// fp32 -> bf16 RNE (manual, used in cvt kernel)
__device__ __forceinline__ u16 f2bf(float f) {
  union { float f; unsigned u; } a; a.f = f;
  unsigned r = a.u + 0x7fffu + ((a.u >> 16) & 1u);
  return (u16)(r >> 16);
}

// fp32 -> bf16 via HW cvt (hot paths)
__device__ __forceinline__ u16 bfbits(float f) {
  union { __bf16 h; u16 u; } c; c.h = (__bf16)f; return c.u;
}

// async global->LDS, 16B per lane; LDS dest must be wave-uniform base + lane*16
__device__ __forceinline__ void gload16(const u16* g, u16* l) {
  __builtin_amdgcn_global_load_lds((const __attribute__((address_space(1))) void*)g,
                                   (__attribute__((address_space(3))) void*)l, 16, 0, 0);
}

// ---------------------------------------------------------------------------
// fp32 -> bf16 conversion of pre_out (4M) + 4 weights (1M each) + mask->bias2
// bias2 = (1-mask) * -10000 * log2(e)  (exp2-domain mask bias)
// ---------------------------------------------------------------------------
__global__ __launch_bounds__(256) void cvt_all(
    const float* __restrict__ X, const float* __restrict__ Wq, const float* __restrict__ Wk,
    const float* __restrict__ Wv, const float* __restrict__ Wo, const float* __restrict__ mask,
    u16* __restrict__ Xb, u16* __restrict__ Wqb, u16* __restrict__ Wkb,
    u16* __restrict__ Wvb, u16* __restrict__ Wob, float* __restrict__ B2) {
  int i = blockIdx.x * 256 + threadIdx.x;   // each thread: 4 elements
  if (i >= (2 << 20)) {                     // mask -> bias2 (4096 floats)
    int off = i - (2 << 20);
    float4 m = ((const float4*)mask)[off];
    float4 o;
    o.x = (1.0f - m.x) * (-10000.0f * 1.44269504f);
    o.y = (1.0f - m.y) * (-10000.0f * 1.44269504f);
    o.z = (1.0f - m.z) * (-10000.0f * 1.44269504f);
    o.w = (1.0f - m.w) * (-10000.0f * 1.44269504f);
    ((float4*)B2)[off] = o;
    return;
  }
  const float* src; u16* dst; int off;
  if (i < (1 << 20)) { src = X; dst = Xb; off = i; }
  else {
    int j = i - (1 << 20);
    int m = j >> 18; off = j & ((1 << 18) - 1);
    src = (m == 0) ? Wq : (m == 1) ? Wk : (m == 2) ? Wv : Wo;
    dst = (m == 0) ? Wqb : (m == 1) ? Wkb : (m == 2) ? Wvb : Wob;
  }
  float4 v = ((const float4*)src)[off];
  u16x4 p; p.x = f2bf(v.x); p.y = f2bf(v.y); p.z = f2bf(v.z); p.w = f2bf(v.w);
  ((u16x4*)dst)[off] = p;
}

// ---------------------------------------------------------------------------
// Fused QKV GEMM (round-8 version, BK=32): 128x128 tile, 4 waves, 4x4 MFMAs.
// mat 0/1 -> Q,K bf16 [s][feature]; mat 2 -> V bf16 transposed [b,h,d,s].
// ---------------------------------------------------------------------------
__global__ __launch_bounds__(256) void qkv_gemm(
    const u16* __restrict__ X,
    const u16* __restrict__ Wq, const u16* __restrict__ Wk, const u16* __restrict__ Wv,
    const float* __restrict__ bq, const float* __restrict__ bk, const float* __restrict__ bv,
    u16* __restrict__ Qo, u16* __restrict__ Ko, u16* __restrict__ Vt) {
  __shared__ u16 As[128 * 32];
  __shared__ u16 Ws[128 * 32];

  const int tid = threadIdx.x;
  const int w = tid >> 6, lane = tid & 63, quad = lane >> 4, l15 = lane & 15;
  const int mat = blockIdx.x >> 3;
  const int col0 = (blockIdx.x & 7) * 128;
  const int row0 = blockIdx.y * 128;
  const u16* W = (mat == 0) ? Wq : (mat == 1) ? Wk : Wv;
  const float* bias = (mat == 0) ? bq : (mat == 1) ? bk : bv;

  const int c0 = tid, c1 = tid + 256;
  const int ar0 = c0 >> 2, al0 = ((c0 & 3) ^ (ar0 & 3)) * 8;
  const int ar1 = c1 >> 2, al1 = ((c1 & 3) ^ (ar1 & 3)) * 8;
  const u16* gA0 = X + (row0 + ar0) * HH + al0;
  const u16* gA1 = X + (row0 + ar1) * HH + al1;
  const u16* gW0 = W + (col0 + ar0) * HH + al0;
  const u16* gW1 = W + (col0 + ar1) * HH + al1;
  u16* lA0 = As + c0 * 8; u16* lA1 = As + c1 * 8;
  u16* lW0 = Ws + c0 * 8; u16* lW1 = Ws + c1 * 8;

  const int wm = (w >> 1) * 64, wn = (w & 1) * 64;
  const int sw = quad ^ (l15 & 3);
  const int aoff = (wm + l15) * 32 + sw * 8;
  const int boff = (wn + l15) * 32 + sw * 8;

  floatx4 acc[4][4];
#pragma unroll
  for (int i = 0; i < 4; i++)
#pragma unroll
    for (int j = 0; j < 4; j++) acc[i][j] = {0.f, 0.f, 0.f, 0.f};

  for (int k0 = 0; k0 < HH; k0 += 32) {
    __syncthreads();
    gload16(gA0 + k0, lA0);
    gload16(gA1 + k0, lA1);
    gload16(gW0 + k0, lW0);
    gload16(gW1 + k0, lW1);
    __syncthreads();
    bf16x8 af[4], bfr[4];
#pragma unroll
    for (int i = 0; i < 4; i++) af[i] = *(const bf16x8*)(As + aoff + i * 512);
#pragma unroll
    for (int j = 0; j < 4; j++) bfr[j] = *(const bf16x8*)(Ws + boff + j * 512);
#pragma unroll
    for (int i = 0; i < 4; i++)
#pragma unroll
      for (int j = 0; j < 4; j++)
        acc[i][j] = __builtin_amdgcn_mfma_f32_16x16x32_bf16(af[i], bfr[j], acc[i][j], 0, 0, 0);
  }

  const int rb = row0 + wm + quad * 4;
  if (mat < 2) {
    u16* O = (mat == 0) ? Qo : Ko;
#pragma unroll
    for (int j = 0; j < 4; j++) {
      const int col = col0 + wn + j * 16 + l15;
      const float bj = bias[col];
#pragma unroll
      for (int i = 0; i < 4; i++) {
        const int r0 = rb + i * 16;
#pragma unroll
        for (int r = 0; r < 4; r++)
          O[(r0 + r) * HH + col] = bfbits(acc[i][j][r] + bj);
      }
    }
  } else {
#pragma unroll
    for (int j = 0; j < 4; j++) {
      const int col = col0 + wn + j * 16 + l15;
      const float bj = bias[col];
      const int h = col >> 6, d = col & 63;
#pragma unroll
      for (int i = 0; i < 4; i++) {
        const int m0 = rb + i * 16;
        const int b = m0 >> 11, s = m0 & 2047;
        u16x4 pk;
#pragma unroll
        for (int r = 0; r < 4; r++) pk[r] = bfbits(acc[i][j][r] + bj);
        *(u16x4*)(Vt + (((b * NHEAD + h) * 64 + d) * SS + s)) = pk;
      }
    }
  }
}

// ---------------------------------------------------------------------------
// Output projection GEMM: Y[4096,1024] fp32 = Ab @ Wo^T + bo
// 128x64 tiles (grid 16x32 = 512 blocks); 4 waves of 2x4 MFMAs. (r8 version)
// ---------------------------------------------------------------------------
__global__ __launch_bounds__(256) void oproj_gemm(
    const u16* __restrict__ A, const u16* __restrict__ W,
    const float* __restrict__ bias, float* __restrict__ Y) {
  __shared__ u16 As[128 * 32];
  __shared__ u16 Ws[64 * 32];

  const int tid = threadIdx.x;
  const int w = tid >> 6, lane = tid & 63, quad = lane >> 4, l15 = lane & 15;
  const int col0 = blockIdx.x * 64;
  const int row0 = blockIdx.y * 128;

  const int c0 = tid, c1 = tid + 256;
  const int ar0 = c0 >> 2, al0 = ((c0 & 3) ^ (ar0 & 3)) * 8;
  const int ar1 = c1 >> 2, al1 = ((c1 & 3) ^ (ar1 & 3)) * 8;
  const u16* gA0 = A + (row0 + ar0) * HH + al0;
  const u16* gA1 = A + (row0 + ar1) * HH + al1;
  const u16* gW0 = W + (col0 + ar0) * HH + al0;   // 64 rows: ar0 in 0..63
  u16* lA0 = As + c0 * 8; u16* lA1 = As + c1 * 8;
  u16* lW0 = Ws + c0 * 8;

  const int wm = w * 32;
  const int sw = quad ^ (l15 & 3);
  const int aoff = (wm + l15) * 32 + sw * 8;
  const int boff = l15 * 32 + sw * 8;

  floatx4 acc[2][4];
#pragma unroll
  for (int i = 0; i < 2; i++)
#pragma unroll
    for (int j = 0; j < 4; j++) acc[i][j] = {0.f, 0.f, 0.f, 0.f};

  for (int k0 = 0; k0 < HH; k0 += 32) {
    __syncthreads();
    gload16(gA0 + k0, lA0);
    gload16(gA1 + k0, lA1);
    if (tid < 256) gload16(gW0 + k0, lW0);
    __syncthreads();
    bf16x8 af[2], bfr[4];
#pragma unroll
    for (int i = 0; i < 2; i++) af[i] = *(const bf16x8*)(As + aoff + i * 512);
#pragma unroll
    for (int j = 0; j < 4; j++) bfr[j] = *(const bf16x8*)(Ws + boff + j * 512);
#pragma unroll
    for (int i = 0; i < 2; i++)
#pragma unroll
      for (int j = 0; j < 4; j++)
        acc[i][j] = __builtin_amdgcn_mfma_f32_16x16x32_bf16(af[i], bfr[j], acc[i][j], 0, 0, 0);
  }

  const int rb = row0 + wm + quad * 4;
#pragma unroll
  for (int j = 0; j < 4; j++) {
    const int col = col0 + j * 16 + l15;
    const float bj = bias[col];
#pragma unroll
    for (int i = 0; i < 2; i++) {
      const int r0 = rb + i * 16;
#pragma unroll
      for (int r = 0; r < 4; r++)
        Y[(r0 + r) * HH + col] = acc[i][j][r] + bj;
    }
  }
}

// ---------------------------------------------------------------------------
// Barrier-free MFMA flash attention. K/V/Q read DIRECTLY from global (L1/L2
// serve reuse; head slices are 128B-aligned rows -> perfect L1 lines).
// LDS holds ONLY the wave-private P buffer -> zero __syncthreads.
//   S^T = K·Q^T (A=K global b128 frags, B=Q hoisted global frags)
//   P^T store: 8 x b64 (C-layout [key=quad*4+r][q=l15] -> Pt[q][key])
//   PV: A = Pt rows (b128, conflict-free), B = Vt rows (global b128)
// Grid (16 qtiles x 128 rows, 32 bh); 4 waves; wave owns 32 q rows.
// ---------------------------------------------------------------------------
#define QT 128

__global__ __launch_bounds__(256, 2) void attn_mfma(
    const u16* __restrict__ Q, const u16* __restrict__ K, const u16* __restrict__ Vt,
    const float* __restrict__ B2, u16* __restrict__ O) {
  __shared__ u16 Pt[4][32 * 72];   // per-wave P[q=0..31][key=0..63], stride 72

  const int qt = blockIdx.x, bh = blockIdx.y;
  const int b = bh >> 4, h = bh & 15;
  const int tid = threadIdx.x;
  const int w = tid >> 6, lane = tid & 63, quad = lane >> 4, l15 = lane & 15;

  const int qbase  = (b * SS + qt * QT) * HH + h * 64;
  const int kvbase = (b * SS) * HH + h * 64;
  const int vtbase = (b * NHEAD + h) * 64 * SS;

  // hoist Q fragments straight from global (B-operand: q=l15, d=quad*8+jj)
  bf16x8 aQ[2][2];
#pragma unroll
  for (int mt = 0; mt < 2; mt++) {
    const u16* qr = Q + qbase + (w * 32 + mt * 16 + l15) * HH;
    aQ[mt][0] = *(const bf16x8*)(qr + quad * 8);
    aQ[mt][1] = *(const bf16x8*)(qr + 32 + quad * 8);
  }

  floatx4 o[2][4];
#pragma unroll
  for (int mt = 0; mt < 2; mt++)
#pragma unroll
    for (int j = 0; j < 4; j++) o[mt][j] = {0.f, 0.f, 0.f, 0.f};
  float lp[2] = {0.f, 0.f};

  u16* Pw = &Pt[w][0];
  const float* B2row = B2 + b * SS;

  for (int kt = 0; kt < 32; kt++) {
    // S^T = K·Q^T : A = K frags (global b128), C-layout [key=quad*4+r][q=l15]
    floatx4 st[2][4];
#pragma unroll
    for (int kb = 0; kb < 4; kb++) {
      const u16* kr = K + kvbase + (kt * 64 + kb * 16 + l15) * HH;
      bf16x8 kf0 = *(const bf16x8*)(kr + quad * 8);
      bf16x8 kf1 = *(const bf16x8*)(kr + 32 + quad * 8);
#pragma unroll
      for (int mt = 0; mt < 2; mt++) {
        floatx4 z = {0.f, 0.f, 0.f, 0.f};
        z = __builtin_amdgcn_mfma_f32_16x16x32_bf16(kf0, aQ[mt][0], z, 0, 0, 0);
        st[mt][kb] = __builtin_amdgcn_mfma_f32_16x16x32_bf16(kf1, aQ[mt][1], z, 0, 0, 0);
      }
    }

    // P^T = exp2(S^T * 0.125*log2e + bias2[key]); l partial per lane (q=l15)
#pragma unroll
    for (int kb = 0; kb < 4; kb++) {
      const floatx4 bb = *(const floatx4*)(B2row + kt * 64 + kb * 16 + quad * 4);
#pragma unroll
      for (int mt = 0; mt < 2; mt++) {
        u16x4 pk;
#pragma unroll
        for (int r = 0; r < 4; r++) {
          const float p = __builtin_amdgcn_exp2f(st[mt][kb][r] * 0.180336880f + bb[r]);
          lp[mt] += p;
          pk[r] = bfbits(p);
        }
        // b64 packed store: Pt[q=l15][key = kb*16 + quad*4 .. +3]
        *(u16x4*)(Pw + (mt * 16 + l15) * 72 + kb * 16 + quad * 4) = pk;
      }
    }

    // pa = P A-frags (b128, conflict-free; same-wave RAW ordered by lgkmcnt)
    bf16x8 pa[2][2];
#pragma unroll
    for (int mt = 0; mt < 2; mt++) {
      const u16* pr = Pw + (mt * 16 + l15) * 72;
      pa[mt][0] = *(const bf16x8*)(pr + quad * 8);
      pa[mt][1] = *(const bf16x8*)(pr + 32 + quad * 8);
    }

    // O += P·V : B = Vt rows (global b128; d=j*16+l15, keys contiguous)
#pragma unroll
    for (int j = 0; j < 4; j++) {
      const u16* vr = Vt + vtbase + (j * 16 + l15) * SS + kt * 64;
      bf16x8 v0 = *(const bf16x8*)(vr + quad * 8);
      bf16x8 v1 = *(const bf16x8*)(vr + 32 + quad * 8);
#pragma unroll
      for (int mt = 0; mt < 2; mt++) {
        o[mt][j] = __builtin_amdgcn_mfma_f32_16x16x32_bf16(pa[mt][0], v0, o[mt][j], 0, 0, 0);
        o[mt][j] = __builtin_amdgcn_mfma_f32_16x16x32_bf16(pa[mt][1], v1, o[mt][j], 0, 0, 0);
      }
    }
  }

  // l: lane holds partial over its quad's keys for q=l15 -> reduce across quads
#pragma unroll
  for (int mt = 0; mt < 2; mt++) {
    float v = lp[mt];
    v += __shfl_xor(v, 16);
    v += __shfl_xor(v, 32);
    lp[mt] = v;   // now: l for q-row l15 (+mt*16), valid in every quad
  }

  // O C-layout rows are quad*4+r -> fetch matching l via bpermute shfl
#pragma unroll
  for (int mt = 0; mt < 2; mt++) {
    const int orow0 = b * SS + qt * QT + w * 32 + mt * 16 + quad * 4;
#pragma unroll
    for (int r = 0; r < 4; r++) {
      const float lr = __shfl(lp[mt], quad * 4 + r);
      const float inv = 1.0f / lr;
#pragma unroll
      for (int j = 0; j < 4; j++)
        O[(orow0 + r) * HH + h * 64 + j * 16 + l15] = bfbits(o[mt][j][r] * inv);
    }
  }
}

// ---------------------------------------------------------------------------
// out = LayerNorm(x0 + y) * w + b
// ---------------------------------------------------------------------------
__device__ __forceinline__ float block_sum256(float v) {
  __shared__ float sb[4];
#pragma unroll
  for (int o = 1; o < 64; o <<= 1) v += __shfl_xor(v, o);
  if ((threadIdx.x & 63) == 0) sb[threadIdx.x >> 6] = v;
  __syncthreads();
  float r = sb[0] + sb[1] + sb[2] + sb[3];
  __syncthreads();
  return r;
}

__global__ __launch_bounds__(256) void add_layernorm(
    const float* __restrict__ x0, const float* __restrict__ y,
    const float* __restrict__ w, const float* __restrict__ b,
    float* __restrict__ out) {
  const int row = blockIdx.x;
  const int t = threadIdx.x;
  const float* xr = x0 + (size_t)row * HH;
  const float* yr = y + (size_t)row * HH;

  float v[4];
  float sum = 0.f;
#pragma unroll
  for (int i = 0; i < 4; i++) {
    int idx = t + i * 256;
    v[i] = xr[idx] + yr[idx];
    sum += v[i];
  }
  float mean = block_sum256(sum) * (1.0f / HH);

  float sq = 0.f;
#pragma unroll
  for (int i = 0; i < 4; i++) {
    float d = v[i] - mean;
    sq += d * d;
  }
  float var = block_sum256(sq) * (1.0f / HH);
  float inv = rsqrtf(var + 1e-12f);

#pragma unroll
  for (int i = 0; i < 4; i++) {
    int idx = t + i * 256;
    out[(size_t)row * HH + idx] = w[idx] * ((v[i] - mean) * inv) + b[idx];
  }
}

// ---------------------------------------------------------------------------
extern "C" void kernel_launch(void* const* d_in, const int* in_sizes, int n_in,
                              void* d_out, int out_size, void* d_ws, size_t ws_size,
                              hipStream_t stream) {
  const float* pre_out = (const float*)d_in[0];
  const float* mask    = (const float*)d_in[1];
  const float* Wq = (const float*)d_in[2];
  const float* bq = (const float*)d_in[3];
  const float* Wk = (const float*)d_in[4];
  const float* bk = (const float*)d_in[5];
  const float* Wv = (const float*)d_in[6];
  const float* bv = (const float*)d_in[7];
  const float* Wo = (const float*)d_in[8];
  const float* bo = (const float*)d_in[9];
  const float* ln_w = (const float*)d_in[10];
  const float* ln_b = (const float*)d_in[11];
  float* out = (float*)d_out;

  // workspace layout
  u16* Xb  = (u16*)d_ws;                // 4M u16
  u16* Wqb = Xb + (4 << 20);            // 1M
  u16* Wkb = Wqb + (1 << 20);
  u16* Wvb = Wkb + (1 << 20);
  u16* Wob = Wvb + (1 << 20);
  u16* Qb  = Wob + (1 << 20);           // 4M
  u16* Kb  = Qb + (4 << 20);            // 4M
  u16* Vtb = Kb + (4 << 20);            // 4M
  u16* Ab  = Vtb + (4 << 20);           // 4M
  float* Yb = (float*)(Ab + (4 << 20)); // 4M fp32
  float* B2 = Yb + (4 << 20);           // 4096 fp32 (mask bias, exp2 domain)

  cvt_all<<<8196, 256, 0, stream>>>(pre_out, Wq, Wk, Wv, Wo, mask,
                                    Xb, Wqb, Wkb, Wvb, Wob, B2);

  qkv_gemm<<<dim3(24, 32), 256, 0, stream>>>(Xb, Wqb, Wkb, Wvb, bq, bk, bv, Qb, Kb, Vtb);

  attn_mfma<<<dim3(SS / QT, BB * NHEAD), 256, 0, stream>>>(Qb, Kb, Vtb, B2, Ab);

  oproj_gemm<<<dim3(16, 32), 256, 0, stream>>>(Ab, Wob, bo, Yb);

  add_layernorm<<<BB * SS, 256, 0, stream>>>(pre_out, Yb, ln_w, ln_b, out);
}

// Round 11
// 231.659 us; speedup vs baseline: 1.3547x; 1.3547x over previous
//
#include <hip/hip_runtime.h>
#include <math.h>

typedef unsigned short u16;
typedef float floatx4 __attribute__((ext_vector_type(4)));
typedef __bf16 bf16x8 __attribute__((ext_vector_type(8)));
typedef u16 u16x4 __attribute__((ext_vector_type(4)));

#define BB 2
#define SS 2048
#define HH 1024
#define NHEAD 16

// fp32 -> bf16 RNE (manual, used in cvt kernel)
__device__ __forceinline__ u16 f2bf(float f) {
  union { float f; unsigned u; } a; a.f = f;
  unsigned r = a.u + 0x7fffu + ((a.u >> 16) & 1u);
  return (u16)(r >> 16);
}

// fp32 -> bf16 via HW cvt (hot paths)
__device__ __forceinline__ u16 bfbits(float f) {
  union { __bf16 h; u16 u; } c; c.h = (__bf16)f; return c.u;
}

// async global->LDS, 16B per lane; LDS dest must be wave-uniform base + lane*16
__device__ __forceinline__ void gload16(const u16* g, u16* l) {
  __builtin_amdgcn_global_load_lds((const __attribute__((address_space(1))) void*)g,
                                   (__attribute__((address_space(3))) void*)l, 16, 0, 0);
}

// ---------------------------------------------------------------------------
// fp32 -> bf16 conversion of pre_out (4M) + 4 weights (1M each) + mask->bias2
// bias2 = (1-mask) * -10000 * log2(e)  (exp2-domain mask bias)
// ---------------------------------------------------------------------------
__global__ __launch_bounds__(256) void cvt_all(
    const float* __restrict__ X, const float* __restrict__ Wq, const float* __restrict__ Wk,
    const float* __restrict__ Wv, const float* __restrict__ Wo, const float* __restrict__ mask,
    u16* __restrict__ Xb, u16* __restrict__ Wqb, u16* __restrict__ Wkb,
    u16* __restrict__ Wvb, u16* __restrict__ Wob, float* __restrict__ B2) {
  int i = blockIdx.x * 256 + threadIdx.x;   // each thread: 4 elements
  if (i >= (2 << 20)) {                     // mask -> bias2 (4096 floats)
    int off = i - (2 << 20);
    float4 m = ((const float4*)mask)[off];
    float4 o;
    o.x = (1.0f - m.x) * (-10000.0f * 1.44269504f);
    o.y = (1.0f - m.y) * (-10000.0f * 1.44269504f);
    o.z = (1.0f - m.z) * (-10000.0f * 1.44269504f);
    o.w = (1.0f - m.w) * (-10000.0f * 1.44269504f);
    ((float4*)B2)[off] = o;
    return;
  }
  const float* src; u16* dst; int off;
  if (i < (1 << 20)) { src = X; dst = Xb; off = i; }
  else {
    int j = i - (1 << 20);
    int m = j >> 18; off = j & ((1 << 18) - 1);
    src = (m == 0) ? Wq : (m == 1) ? Wk : (m == 2) ? Wv : Wo;
    dst = (m == 0) ? Wqb : (m == 1) ? Wkb : (m == 2) ? Wvb : Wob;
  }
  float4 v = ((const float4*)src)[off];
  u16x4 p; p.x = f2bf(v.x); p.y = f2bf(v.y); p.z = f2bf(v.z); p.w = f2bf(v.w);
  ((u16x4*)dst)[off] = p;
}

// ---------------------------------------------------------------------------
// Fused QKV GEMM (round-8 version, BK=32): 128x128 tile, 4 waves, 4x4 MFMAs.
// mat 0/1 -> Q,K bf16 [s][feature]; mat 2 -> V bf16 transposed [b,h,d,s].
// ---------------------------------------------------------------------------
__global__ __launch_bounds__(256) void qkv_gemm(
    const u16* __restrict__ X,
    const u16* __restrict__ Wq, const u16* __restrict__ Wk, const u16* __restrict__ Wv,
    const float* __restrict__ bq, const float* __restrict__ bk, const float* __restrict__ bv,
    u16* __restrict__ Qo, u16* __restrict__ Ko, u16* __restrict__ Vt) {
  __shared__ u16 As[128 * 32];
  __shared__ u16 Ws[128 * 32];

  const int tid = threadIdx.x;
  const int w = tid >> 6, lane = tid & 63, quad = lane >> 4, l15 = lane & 15;
  const int mat = blockIdx.x >> 3;
  const int col0 = (blockIdx.x & 7) * 128;
  const int row0 = blockIdx.y * 128;
  const u16* W = (mat == 0) ? Wq : (mat == 1) ? Wk : Wv;
  const float* bias = (mat == 0) ? bq : (mat == 1) ? bk : bv;

  const int c0 = tid, c1 = tid + 256;
  const int ar0 = c0 >> 2, al0 = ((c0 & 3) ^ (ar0 & 3)) * 8;
  const int ar1 = c1 >> 2, al1 = ((c1 & 3) ^ (ar1 & 3)) * 8;
  const u16* gA0 = X + (row0 + ar0) * HH + al0;
  const u16* gA1 = X + (row0 + ar1) * HH + al1;
  const u16* gW0 = W + (col0 + ar0) * HH + al0;
  const u16* gW1 = W + (col0 + ar1) * HH + al1;
  u16* lA0 = As + c0 * 8; u16* lA1 = As + c1 * 8;
  u16* lW0 = Ws + c0 * 8; u16* lW1 = Ws + c1 * 8;

  const int wm = (w >> 1) * 64, wn = (w & 1) * 64;
  const int sw = quad ^ (l15 & 3);
  const int aoff = (wm + l15) * 32 + sw * 8;
  const int boff = (wn + l15) * 32 + sw * 8;

  floatx4 acc[4][4];
#pragma unroll
  for (int i = 0; i < 4; i++)
#pragma unroll
    for (int j = 0; j < 4; j++) acc[i][j] = {0.f, 0.f, 0.f, 0.f};

  for (int k0 = 0; k0 < HH; k0 += 32) {
    __syncthreads();
    gload16(gA0 + k0, lA0);
    gload16(gA1 + k0, lA1);
    gload16(gW0 + k0, lW0);
    gload16(gW1 + k0, lW1);
    __syncthreads();
    bf16x8 af[4], bfr[4];
#pragma unroll
    for (int i = 0; i < 4; i++) af[i] = *(const bf16x8*)(As + aoff + i * 512);
#pragma unroll
    for (int j = 0; j < 4; j++) bfr[j] = *(const bf16x8*)(Ws + boff + j * 512);
#pragma unroll
    for (int i = 0; i < 4; i++)
#pragma unroll
      for (int j = 0; j < 4; j++)
        acc[i][j] = __builtin_amdgcn_mfma_f32_16x16x32_bf16(af[i], bfr[j], acc[i][j], 0, 0, 0);
  }

  const int rb = row0 + wm + quad * 4;
  if (mat < 2) {
    u16* O = (mat == 0) ? Qo : Ko;
#pragma unroll
    for (int j = 0; j < 4; j++) {
      const int col = col0 + wn + j * 16 + l15;
      const float bj = bias[col];
#pragma unroll
      for (int i = 0; i < 4; i++) {
        const int r0 = rb + i * 16;
#pragma unroll
        for (int r = 0; r < 4; r++)
          O[(r0 + r) * HH + col] = bfbits(acc[i][j][r] + bj);
      }
    }
  } else {
#pragma unroll
    for (int j = 0; j < 4; j++) {
      const int col = col0 + wn + j * 16 + l15;
      const float bj = bias[col];
      const int h = col >> 6, d = col & 63;
#pragma unroll
      for (int i = 0; i < 4; i++) {
        const int m0 = rb + i * 16;
        const int b = m0 >> 11, s = m0 & 2047;
        u16x4 pk;
#pragma unroll
        for (int r = 0; r < 4; r++) pk[r] = bfbits(acc[i][j][r] + bj);
        *(u16x4*)(Vt + (((b * NHEAD + h) * 64 + d) * SS + s)) = pk;
      }
    }
  }
}

// ---------------------------------------------------------------------------
// Output projection GEMM: Y[4096,1024] fp32 = Ab @ Wo^T + bo
// 128x64 tiles (grid 16x32 = 512 blocks); 4 waves of 2x4 MFMAs. (r8 version)
// ---------------------------------------------------------------------------
__global__ __launch_bounds__(256) void oproj_gemm(
    const u16* __restrict__ A, const u16* __restrict__ W,
    const float* __restrict__ bias, float* __restrict__ Y) {
  __shared__ u16 As[128 * 32];
  __shared__ u16 Ws[64 * 32];

  const int tid = threadIdx.x;
  const int w = tid >> 6, lane = tid & 63, quad = lane >> 4, l15 = lane & 15;
  const int col0 = blockIdx.x * 64;
  const int row0 = blockIdx.y * 128;

  const int c0 = tid, c1 = tid + 256;
  const int ar0 = c0 >> 2, al0 = ((c0 & 3) ^ (ar0 & 3)) * 8;
  const int ar1 = c1 >> 2, al1 = ((c1 & 3) ^ (ar1 & 3)) * 8;
  const u16* gA0 = A + (row0 + ar0) * HH + al0;
  const u16* gA1 = A + (row0 + ar1) * HH + al1;
  const u16* gW0 = W + (col0 + ar0) * HH + al0;   // 64 rows: ar0 in 0..63
  u16* lA0 = As + c0 * 8; u16* lA1 = As + c1 * 8;
  u16* lW0 = Ws + c0 * 8;

  const int wm = w * 32;
  const int sw = quad ^ (l15 & 3);
  const int aoff = (wm + l15) * 32 + sw * 8;
  const int boff = l15 * 32 + sw * 8;

  floatx4 acc[2][4];
#pragma unroll
  for (int i = 0; i < 2; i++)
#pragma unroll
    for (int j = 0; j < 4; j++) acc[i][j] = {0.f, 0.f, 0.f, 0.f};

  for (int k0 = 0; k0 < HH; k0 += 32) {
    __syncthreads();
    gload16(gA0 + k0, lA0);
    gload16(gA1 + k0, lA1);
    if (tid < 256) gload16(gW0 + k0, lW0);
    __syncthreads();
    bf16x8 af[2], bfr[4];
#pragma unroll
    for (int i = 0; i < 2; i++) af[i] = *(const bf16x8*)(As + aoff + i * 512);
#pragma unroll
    for (int j = 0; j < 4; j++) bfr[j] = *(const bf16x8*)(Ws + boff + j * 512);
#pragma unroll
    for (int i = 0; i < 2; i++)
#pragma unroll
      for (int j = 0; j < 4; j++)
        acc[i][j] = __builtin_amdgcn_mfma_f32_16x16x32_bf16(af[i], bfr[j], acc[i][j], 0, 0, 0);
  }

  const int rb = row0 + wm + quad * 4;
#pragma unroll
  for (int j = 0; j < 4; j++) {
    const int col = col0 + j * 16 + l15;
    const float bj = bias[col];
#pragma unroll
    for (int i = 0; i < 2; i++) {
      const int r0 = rb + i * 16;
#pragma unroll
      for (int r = 0; r < 4; r++)
        Y[(r0 + r) * HH + col] = acc[i][j][r] + bj;
    }
  }
}

// ---------------------------------------------------------------------------
// MFMA flash attention (round-8 skeleton) with TRANSPOSED score MFMA:
//   S^T = K·Q^T  -- operand swap only; K/Q ds_read_b128 addresses identical
//   C-layout [key=quad*4+r][q=l15]  ->  P store = 8 packed b64 (vs 32 b16)
//   PV unchanged: A = P rows (b128 at q*72), B = V rows from Vs
// l: per-lane (q=l15) partial, quad-reduce at end, shfl-broadcast in epilogue.
// Grid (16 qtiles of 128 rows, 32 bh); 4 waves; wave owns 32 q rows.
// ---------------------------------------------------------------------------
#define QT 128

__global__ __launch_bounds__(256, 3) void attn_mfma(
    const u16* __restrict__ Q, const u16* __restrict__ K, const u16* __restrict__ Vt,
    const float* __restrict__ B2, u16* __restrict__ O) {
  __shared__ u16 UQ[9216];   // Qs [128][64] (8192) ∪ Ps (wave w at w*2304, [32][72])
  __shared__ u16 Ks[64 * 64];
  __shared__ u16 Vs[64 * 64];

  const int qt = blockIdx.x, bh = blockIdx.y;
  const int b = bh >> 4, h = bh & 15;
  const int tid = threadIdx.x;
  const int w = tid >> 6, lane = tid & 63, quad = lane >> 4, l15 = lane & 15;
  const int sw = l15 & 7;

  const int qbase  = (b * SS + qt * QT) * HH + h * 64;
  const int kvbase = (b * SS) * HH + h * 64;
  const int vtbase = (b * NHEAD + h) * 64 * SS;

  // stage Q tile: 128 rows x 128B, chunk swizzle pc = lc ^ (r&7)
#pragma unroll
  for (int i = 0; i < 4; i++) {
    const int c = tid + i * 256;
    const int r = c >> 3, lc = (c & 7) ^ (r & 7);
    gload16(Q + qbase + r * HH + lc * 8, UQ + c * 8);
  }
  __syncthreads();

  // hoist Q fragments (B-operand of S^T: n=q=l15, k=quad*8+jj) — same reads
  bf16x8 aQ[2][2];
#pragma unroll
  for (int mt = 0; mt < 2; mt++) {
    const u16* qr = UQ + (w * 32 + mt * 16 + l15) * 64;
    aQ[mt][0] = *(const bf16x8*)(qr + ((quad ^ sw) * 8));
    aQ[mt][1] = *(const bf16x8*)(qr + (((4 + quad) ^ sw) * 8));
  }

  floatx4 o[2][4];
#pragma unroll
  for (int mt = 0; mt < 2; mt++)
#pragma unroll
    for (int j = 0; j < 4; j++) o[mt][j] = {0.f, 0.f, 0.f, 0.f};
  float lp[2] = {0.f, 0.f};

  u16* Pw = UQ + w * 2304;
  const float* B2row = B2 + b * SS;

  for (int kt = 0; kt < 32; kt++) {
    __syncthreads();   // all waves done reading Ks/Vs (iter 0: done reading Q)
#pragma unroll
    for (int i = 0; i < 2; i++) {
      const int c = tid + i * 256;
      const int r = c >> 3, lc = (c & 7) ^ (r & 7);
      gload16(K + kvbase + (kt * 64 + r) * HH + lc * 8, Ks + c * 8);
      gload16(Vt + vtbase + r * SS + kt * 64 + lc * 8, Vs + c * 8);
    }
    __syncthreads();

    // S^T = K·Q^T : A = K frags (rows kb*16+l15, same ds_read_b128 as before)
    floatx4 st[2][4];
#pragma unroll
    for (int kb = 0; kb < 4; kb++) {
      const u16* kr = Ks + (kb * 16 + l15) * 64;
      bf16x8 kf0 = *(const bf16x8*)(kr + ((quad ^ sw) * 8));
      bf16x8 kf1 = *(const bf16x8*)(kr + (((4 + quad) ^ sw) * 8));
#pragma unroll
      for (int mt = 0; mt < 2; mt++) {
        floatx4 z = {0.f, 0.f, 0.f, 0.f};
        z = __builtin_amdgcn_mfma_f32_16x16x32_bf16(kf0, aQ[mt][0], z, 0, 0, 0);
        st[mt][kb] = __builtin_amdgcn_mfma_f32_16x16x32_bf16(kf1, aQ[mt][1], z, 0, 0, 0);
      }
    }

    // P^T = exp2(S^T*0.125*log2e + bias2[key]); packed b64 store into P[q][key]
#pragma unroll
    for (int kb = 0; kb < 4; kb++) {
      const floatx4 bb = *(const floatx4*)(B2row + kt * 64 + kb * 16 + quad * 4);
#pragma unroll
      for (int mt = 0; mt < 2; mt++) {
        u16x4 pk;
#pragma unroll
        for (int r = 0; r < 4; r++) {
          const float p = __builtin_amdgcn_exp2f(st[mt][kb][r] * 0.180336880f + bb[r]);
          lp[mt] += p;
          pk[r] = bfbits(p);
        }
        *(u16x4*)(Pw + (mt * 16 + l15) * 72 + kb * 16 + quad * 4) = pk;
      }
    }

    // PV (A = P rows, b128, conflict-free; same-wave RAW ordered by lgkmcnt)
    bf16x8 pa[2][2];
#pragma unroll
    for (int mt = 0; mt < 2; mt++) {
      const u16* pr = Pw + (mt * 16 + l15) * 72;
      pa[mt][0] = *(const bf16x8*)(pr + quad * 8);
      pa[mt][1] = *(const bf16x8*)(pr + 32 + quad * 8);
    }
#pragma unroll
    for (int j = 0; j < 4; j++) {
      const u16* vr = Vs + (j * 16 + l15) * 64;
      bf16x8 v0 = *(const bf16x8*)(vr + ((quad ^ sw) * 8));
      bf16x8 v1 = *(const bf16x8*)(vr + (((4 + quad) ^ sw) * 8));
#pragma unroll
      for (int mt = 0; mt < 2; mt++) {
        o[mt][j] = __builtin_amdgcn_mfma_f32_16x16x32_bf16(pa[mt][0], v0, o[mt][j], 0, 0, 0);
        o[mt][j] = __builtin_amdgcn_mfma_f32_16x16x32_bf16(pa[mt][1], v1, o[mt][j], 0, 0, 0);
      }
    }
  }

  // l: lane's partial covers its quad's keys for q=l15 -> reduce across quads
#pragma unroll
  for (int mt = 0; mt < 2; mt++) {
    float v = lp[mt];
    v += __shfl_xor(v, 16);
    v += __shfl_xor(v, 32);
    lp[mt] = v;   // l for q-row (mt*16 + l15), valid in every quad
  }

  // O C-layout rows are quad*4+r -> fetch matching l via lane broadcast
#pragma unroll
  for (int mt = 0; mt < 2; mt++) {
    const int orow0 = b * SS + qt * QT + w * 32 + mt * 16 + quad * 4;
#pragma unroll
    for (int r = 0; r < 4; r++) {
      const float inv = 1.0f / __shfl(lp[mt], quad * 4 + r);
#pragma unroll
      for (int j = 0; j < 4; j++)
        O[(orow0 + r) * HH + h * 64 + j * 16 + l15] = bfbits(o[mt][j][r] * inv);
    }
  }
}

// ---------------------------------------------------------------------------
// out = LayerNorm(x0 + y) * w + b
// ---------------------------------------------------------------------------
__device__ __forceinline__ float block_sum256(float v) {
  __shared__ float sb[4];
#pragma unroll
  for (int o = 1; o < 64; o <<= 1) v += __shfl_xor(v, o);
  if ((threadIdx.x & 63) == 0) sb[threadIdx.x >> 6] = v;
  __syncthreads();
  float r = sb[0] + sb[1] + sb[2] + sb[3];
  __syncthreads();
  return r;
}

__global__ __launch_bounds__(256) void add_layernorm(
    const float* __restrict__ x0, const float* __restrict__ y,
    const float* __restrict__ w, const float* __restrict__ b,
    float* __restrict__ out) {
  const int row = blockIdx.x;
  const int t = threadIdx.x;
  const float* xr = x0 + (size_t)row * HH;
  const float* yr = y + (size_t)row * HH;

  float v[4];
  float sum = 0.f;
#pragma unroll
  for (int i = 0; i < 4; i++) {
    int idx = t + i * 256;
    v[i] = xr[idx] + yr[idx];
    sum += v[i];
  }
  float mean = block_sum256(sum) * (1.0f / HH);

  float sq = 0.f;
#pragma unroll
  for (int i = 0; i < 4; i++) {
    float d = v[i] - mean;
    sq += d * d;
  }
  float var = block_sum256(sq) * (1.0f / HH);
  float inv = rsqrtf(var + 1e-12f);

#pragma unroll
  for (int i = 0; i < 4; i++) {
    int idx = t + i * 256;
    out[(size_t)row * HH + idx] = w[idx] * ((v[i] - mean) * inv) + b[idx];
  }
}

// ---------------------------------------------------------------------------
extern "C" void kernel_launch(void* const* d_in, const int* in_sizes, int n_in,
                              void* d_out, int out_size, void* d_ws, size_t ws_size,
                              hipStream_t stream) {
  const float* pre_out = (const float*)d_in[0];
  const float* mask    = (const float*)d_in[1];
  const float* Wq = (const float*)d_in[2];
  const float* bq = (const float*)d_in[3];
  const float* Wk = (const float*)d_in[4];
  const float* bk = (const float*)d_in[5];
  const float* Wv = (const float*)d_in[6];
  const float* bv = (const float*)d_in[7];
  const float* Wo = (const float*)d_in[8];
  const float* bo = (const float*)d_in[9];
  const float* ln_w = (const float*)d_in[10];
  const float* ln_b = (const float*)d_in[11];
  float* out = (float*)d_out;

  // workspace layout
  u16* Xb  = (u16*)d_ws;                // 4M u16
  u16* Wqb = Xb + (4 << 20);            // 1M
  u16* Wkb = Wqb + (1 << 20);
  u16* Wvb = Wkb + (1 << 20);
  u16* Wob = Wvb + (1 << 20);
  u16* Qb  = Wob + (1 << 20);           // 4M
  u16* Kb  = Qb + (4 << 20);            // 4M
  u16* Vtb = Kb + (4 << 20);            // 4M
  u16* Ab  = Vtb + (4 << 20);           // 4M
  float* Yb = (float*)(Ab + (4 << 20)); // 4M fp32
  float* B2 = Yb + (4 << 20);           // 4096 fp32 (mask bias, exp2 domain)

  cvt_all<<<8196, 256, 0, stream>>>(pre_out, Wq, Wk, Wv, Wo, mask,
                                    Xb, Wqb, Wkb, Wvb, Wob, B2);

  qkv_gemm<<<dim3(24, 32), 256, 0, stream>>>(Xb, Wqb, Wkb, Wvb, bq, bk, bv, Qb, Kb, Vtb);

  attn_mfma<<<dim3(SS / QT, BB * NHEAD), 256, 0, stream>>>(Qb, Kb, Vtb, B2, Ab);

  oproj_gemm<<<dim3(16, 32), 256, 0, stream>>>(Ab, Wob, bo, Yb);

  add_layernorm<<<BB * SS, 256, 0, stream>>>(pre_out, Yb, ln_w, ln_b, out);
}